// Round 1
// baseline (55.359 us; speedup 1.0000x reference)
//
#include <hip/hip_runtime.h>

// out[i] = state[i] * factor, factor = prod over 30 gates of
// (2 cos(a) cos(b) + 2j sin(a) sin(g)).  Output complex64 interleaved.

__device__ __forceinline__ void compute_factor(const float* __restrict__ gp,
                                               float& fr_out, float& fi_out) {
    // 30 gates, 4 params each (delta unused). Double accumulation: cheap, accurate.
    double re = 1.0, im = 0.0;
    for (int i = 0; i < 30; ++i) {
        double a = (double)gp[i * 4 + 0];
        double b = (double)gp[i * 4 + 1];
        double g = (double)gp[i * 4 + 2];
        double sr = 2.0 * cos(a) * cos(b);
        double si = 2.0 * sin(a) * sin(g);
        double nre = re * sr - im * si;
        double nim = re * si + im * sr;
        re = nre;
        im = nim;
    }
    fr_out = (float)re;
    fi_out = (float)im;
}

__global__ void qp_complex_kernel(const float* __restrict__ state,
                                  const float* __restrict__ gp,
                                  float* __restrict__ out,  // interleaved re,im
                                  long long n2 /* N/2 float2 elements */) {
    __shared__ float s_fr, s_fi;
    if (threadIdx.x == 0) {
        compute_factor(gp, s_fr, s_fi);
    }
    __syncthreads();
    const float fr = s_fr, fi = s_fi;

    const long long stride = (long long)gridDim.x * blockDim.x;
    const float2* __restrict__ in2 = reinterpret_cast<const float2*>(state);
    float4* __restrict__ out4 = reinterpret_cast<float4*>(out);
    for (long long i = (long long)blockIdx.x * blockDim.x + threadIdx.x; i < n2; i += stride) {
        float2 s = in2[i];
        float4 o;
        o.x = s.x * fr;
        o.y = s.x * fi;
        o.z = s.y * fr;
        o.w = s.y * fi;
        out4[i] = o;
    }
}

// Fallback if harness exposes out_size == N (real part only).
__global__ void qp_real_kernel(const float* __restrict__ state,
                               const float* __restrict__ gp,
                               float* __restrict__ out,
                               long long n) {
    __shared__ float s_fr, s_fi;
    if (threadIdx.x == 0) {
        compute_factor(gp, s_fr, s_fi);
    }
    __syncthreads();
    const float fr = s_fr;

    const long long stride = (long long)gridDim.x * blockDim.x;
    for (long long i = (long long)blockIdx.x * blockDim.x + threadIdx.x; i < n; i += stride) {
        out[i] = state[i] * fr;
    }
}

extern "C" void kernel_launch(void* const* d_in, const int* in_sizes, int n_in,
                              void* d_out, int out_size, void* d_ws, size_t ws_size,
                              hipStream_t stream) {
    const float* state = (const float*)d_in[0];
    const float* gp = (const float*)d_in[1];
    float* out = (float*)d_out;

    const long long N = (long long)in_sizes[0];  // 8*2048*1024 = 16,777,216

    if ((long long)out_size == 2 * N) {
        // complex64 interleaved: N/2 threads-worth of float2-in / float4-out
        const long long n2 = N / 2;
        const int block = 256;
        const int grid = 2048;  // grid-stride; ~8 blocks/CU territory
        qp_complex_kernel<<<grid, block, 0, stream>>>(state, gp, out, n2);
    } else {
        const int block = 256;
        const int grid = 2048;
        qp_real_kernel<<<grid, block, 0, stream>>>(state, gp, out, N);
    }
}

// Round 2
// 48.291 us; speedup vs baseline: 1.1464x; 1.1464x over previous
//
#include <hip/hip_runtime.h>

// out[i] = Re(state[i] * factor)  (harness exposes real part only: out_size == N)
// factor = prod over 30 gates of (2 cos(a) cos(b) + 2j sin(a) sin(g)).

__global__ void factor_kernel(const float* __restrict__ gp, float* __restrict__ f) {
    // single thread; double accumulation for accuracy
    double re = 1.0, im = 0.0;
    for (int i = 0; i < 30; ++i) {
        double a = (double)gp[i * 4 + 0];
        double b = (double)gp[i * 4 + 1];
        double g = (double)gp[i * 4 + 2];
        double sr = 2.0 * cos(a) * cos(b);
        double si = 2.0 * sin(a) * sin(g);
        double nre = re * sr - im * si;
        double nim = re * si + im * sr;
        re = nre;
        im = nim;
    }
    f[0] = (float)re;
    f[1] = (float)im;
}

// Real-only output path (out_size == N): out = state * fr, float4 both ways.
__global__ void __launch_bounds__(256) qp_real_kernel(const float* __restrict__ state,
                                                      const float* __restrict__ f,
                                                      float* __restrict__ out,
                                                      long long n4 /* N/4 */) {
    const float fr = f[0];
    const float4* __restrict__ in4 = reinterpret_cast<const float4*>(state);
    float4* __restrict__ out4 = reinterpret_cast<float4*>(out);
    const long long stride = (long long)gridDim.x * blockDim.x;
    for (long long i = (long long)blockIdx.x * blockDim.x + threadIdx.x; i < n4; i += stride) {
        float4 s = in4[i];
        float4 o;
        o.x = s.x * fr;
        o.y = s.y * fr;
        o.z = s.z * fr;
        o.w = s.w * fr;
        out4[i] = o;
    }
}

// Defensive: complex64 interleaved output path (out_size == 2N).
__global__ void __launch_bounds__(256) qp_complex_kernel(const float* __restrict__ state,
                                                         const float* __restrict__ f,
                                                         float* __restrict__ out,
                                                         long long n2 /* N/2 */) {
    const float fr = f[0], fi = f[1];
    const float2* __restrict__ in2 = reinterpret_cast<const float2*>(state);
    float4* __restrict__ out4 = reinterpret_cast<float4*>(out);
    const long long stride = (long long)gridDim.x * blockDim.x;
    for (long long i = (long long)blockIdx.x * blockDim.x + threadIdx.x; i < n2; i += stride) {
        float2 s = in2[i];
        float4 o;
        o.x = s.x * fr;
        o.y = s.x * fi;
        o.z = s.y * fr;
        o.w = s.y * fi;
        out4[i] = o;
    }
}

extern "C" void kernel_launch(void* const* d_in, const int* in_sizes, int n_in,
                              void* d_out, int out_size, void* d_ws, size_t ws_size,
                              hipStream_t stream) {
    const float* state = (const float*)d_in[0];
    const float* gp = (const float*)d_in[1];
    float* out = (float*)d_out;
    float* fws = (float*)d_ws;

    const long long N = (long long)in_sizes[0];  // 16,777,216

    factor_kernel<<<1, 1, 0, stream>>>(gp, fws);

    const int block = 256;
    const int grid = 2048;  // grid-stride, 8 blocks/CU territory

    if ((long long)out_size == 2 * N) {
        qp_complex_kernel<<<grid, block, 0, stream>>>(state, fws, out, N / 2);
    } else {
        qp_real_kernel<<<grid, block, 0, stream>>>(state, fws, out, N / 4);
    }
}

// Round 3
// 26.475 us; speedup vs baseline: 2.0910x; 1.8240x over previous
//
#include <hip/hip_runtime.h>

// out[i] = Re(state[i] * factor)   (harness: out_size == N, real part)
// factor = prod over 30 gates of (2 cos(a) cos(b) + 2j sin(a) sin(g)).
// Factor is recomputed per block by wave 0 (lanes 0-29 in parallel + shuffle
// butterfly product) -- ~0.3us latency, fully overlapped; no extra kernel.

__device__ __forceinline__ float2 block_factor(const float* __restrict__ gp) {
    __shared__ float2 sf;
    if (threadIdx.x < 64) {
        const int lane = threadIdx.x;
        float re = 1.0f, im = 0.0f;
        if (lane < 30) {
            const float a = gp[lane * 4 + 0];
            const float b = gp[lane * 4 + 1];
            const float g = gp[lane * 4 + 2];
            re = 2.0f * cosf(a) * cosf(b);
            im = 2.0f * sinf(a) * sinf(g);
        }
        // 64-lane butterfly complex product (identity for lanes >= 30)
        #pragma unroll
        for (int m = 1; m < 64; m <<= 1) {
            const float ore = __shfl_xor(re, m, 64);
            const float oim = __shfl_xor(im, m, 64);
            const float nre = re * ore - im * oim;
            const float nim = re * oim + im * ore;
            re = nre;
            im = nim;
        }
        if (lane == 0) sf = make_float2(re, im);
    }
    __syncthreads();
    return sf;
}

// Real-only output path (out_size == N): out = state * fr, float4 both ways.
__global__ void __launch_bounds__(256) qp_real_kernel(const float* __restrict__ state,
                                                      const float* __restrict__ gp,
                                                      float* __restrict__ out,
                                                      long long n4 /* N/4 */) {
    const float2 f = block_factor(gp);
    const float fr = f.x;
    const float4* __restrict__ in4 = reinterpret_cast<const float4*>(state);
    float4* __restrict__ out4 = reinterpret_cast<float4*>(out);
    const long long stride = (long long)gridDim.x * blockDim.x;
    for (long long i = (long long)blockIdx.x * blockDim.x + threadIdx.x; i < n4; i += stride) {
        float4 s = in4[i];
        float4 o;
        o.x = s.x * fr;
        o.y = s.y * fr;
        o.z = s.z * fr;
        o.w = s.w * fr;
        out4[i] = o;
    }
}

// Defensive: complex64 interleaved output path (out_size == 2N).
__global__ void __launch_bounds__(256) qp_complex_kernel(const float* __restrict__ state,
                                                         const float* __restrict__ gp,
                                                         float* __restrict__ out,
                                                         long long n2 /* N/2 */) {
    const float2 f = block_factor(gp);
    const float fr = f.x, fi = f.y;
    const float2* __restrict__ in2 = reinterpret_cast<const float2*>(state);
    float4* __restrict__ out4 = reinterpret_cast<float4*>(out);
    const long long stride = (long long)gridDim.x * blockDim.x;
    for (long long i = (long long)blockIdx.x * blockDim.x + threadIdx.x; i < n2; i += stride) {
        float2 s = in2[i];
        float4 o;
        o.x = s.x * fr;
        o.y = s.x * fi;
        o.z = s.y * fr;
        o.w = s.y * fi;
        out4[i] = o;
    }
}

extern "C" void kernel_launch(void* const* d_in, const int* in_sizes, int n_in,
                              void* d_out, int out_size, void* d_ws, size_t ws_size,
                              hipStream_t stream) {
    const float* state = (const float*)d_in[0];
    const float* gp = (const float*)d_in[1];
    float* out = (float*)d_out;

    const long long N = (long long)in_sizes[0];  // 16,777,216

    const int block = 256;
    const int grid = 2048;  // grid-stride; ~8 blocks/CU

    if ((long long)out_size == 2 * N) {
        qp_complex_kernel<<<grid, block, 0, stream>>>(state, gp, out, N / 2);
    } else {
        qp_real_kernel<<<grid, block, 0, stream>>>(state, gp, out, N / 4);
    }
}

// Round 5
// 25.833 us; speedup vs baseline: 2.1430x; 1.0249x over previous
//
#include <hip/hip_runtime.h>

// out[i] = Re(state[i] * factor)   (harness: out_size == N, real part)
// factor = prod over 30 gates of (2 cos(a) cos(b) + 2j sin(a) sin(g)).
// Every wave computes the factor redundantly in-register (no LDS, no
// __syncthreads): lanes 0-29 do one gate each, then a 6-step shuffle
// butterfly complex product. ~120 VALU ops/wave -- noise vs 8 float4 iters.

typedef float fvec4 __attribute__((ext_vector_type(4)));  // native vec: ok for nontemporal builtin

__device__ __forceinline__ float2 wave_factor(const float* __restrict__ gp) {
    const int lane = threadIdx.x & 63;
    float re = 1.0f, im = 0.0f;
    if (lane < 30) {
        const float a = gp[lane * 4 + 0];
        const float b = gp[lane * 4 + 1];
        const float g = gp[lane * 4 + 2];
        re = 2.0f * cosf(a) * cosf(b);
        im = 2.0f * sinf(a) * sinf(g);
    }
    #pragma unroll
    for (int m = 1; m < 64; m <<= 1) {
        const float ore = __shfl_xor(re, m, 64);
        const float oim = __shfl_xor(im, m, 64);
        const float nre = re * ore - im * oim;
        const float nim = re * oim + im * ore;
        re = nre;
        im = nim;
    }
    return make_float2(re, im);
}

// Real-only output path (out_size == N): out = state * fr, float4 both ways,
// nontemporal stores (output never re-read -> don't evict state from L3).
__global__ void __launch_bounds__(256) qp_real_kernel(const float* __restrict__ state,
                                                      const float* __restrict__ gp,
                                                      float* __restrict__ out,
                                                      long long n4 /* N/4 */) {
    const float fr = wave_factor(gp).x;
    const fvec4* __restrict__ in4 = reinterpret_cast<const fvec4*>(state);
    fvec4* __restrict__ out4 = reinterpret_cast<fvec4*>(out);
    const long long stride = (long long)gridDim.x * blockDim.x;
    for (long long i = (long long)blockIdx.x * blockDim.x + threadIdx.x; i < n4; i += stride) {
        fvec4 s = in4[i];
        fvec4 o = s * fr;
        __builtin_nontemporal_store(o, &out4[i]);
    }
}

// Defensive: complex64 interleaved output path (out_size == 2N).
__global__ void __launch_bounds__(256) qp_complex_kernel(const float* __restrict__ state,
                                                         const float* __restrict__ gp,
                                                         float* __restrict__ out,
                                                         long long n2 /* N/2 */) {
    const float2 f = wave_factor(gp);
    const float fr = f.x, fi = f.y;
    const float2* __restrict__ in2 = reinterpret_cast<const float2*>(state);
    fvec4* __restrict__ out4 = reinterpret_cast<fvec4*>(out);
    const long long stride = (long long)gridDim.x * blockDim.x;
    for (long long i = (long long)blockIdx.x * blockDim.x + threadIdx.x; i < n2; i += stride) {
        float2 s = in2[i];
        fvec4 o;
        o.x = s.x * fr;
        o.y = s.x * fi;
        o.z = s.y * fr;
        o.w = s.y * fi;
        __builtin_nontemporal_store(o, &out4[i]);
    }
}

extern "C" void kernel_launch(void* const* d_in, const int* in_sizes, int n_in,
                              void* d_out, int out_size, void* d_ws, size_t ws_size,
                              hipStream_t stream) {
    const float* state = (const float*)d_in[0];
    const float* gp = (const float*)d_in[1];
    float* out = (float*)d_out;

    const long long N = (long long)in_sizes[0];  // 16,777,216

    const int block = 256;
    const int grid = 4096;  // grid-stride; shorter per-thread loop, small tail

    if ((long long)out_size == 2 * N) {
        qp_complex_kernel<<<grid, block, 0, stream>>>(state, gp, out, N / 2);
    } else {
        qp_real_kernel<<<grid, block, 0, stream>>>(state, gp, out, N / 4);
    }
}